// Round 5
// baseline (320.052 us; speedup 1.0000x reference)
//
#include <hip/hip_runtime.h>
#include <hip/hip_bf16.h>
#include <cmath>

typedef unsigned short u16;
typedef __attribute__((ext_vector_type(8))) short bf16x8;
typedef __attribute__((ext_vector_type(4))) float f32x4;
typedef __attribute__((ext_vector_type(2))) unsigned short u16x2;
typedef __attribute__((ext_vector_type(4))) unsigned short u16x4;

// Problem constants: B=8, C=128, H=128, WIN=4, K=3, WS=64, L=16384
// Workspace layout (bytes):
#define OFF_WW    81920u      // 32 f32
#define OFF_R     82048u      // R2[w][t][c] f32 = 18432
#define OFF_FSUM  100480u     // 128 f32
#define OFF_GKT   100992u     // 4*128*128 f32 = 262144
#define OFF_PART  363136u     // part[b][128r][2j][3s][128c] f32 = 3145728 (dead A2 slot)
#define OFF_M     5081728u    // M[w][t][o][c] f32 = 2359296
#define OFF_KEFF  7441024u    // keff_t[b][t][cb][o][8c] u16 = 2359296 ; cw2 (f32) during prep
#define OFF_XPAD  9800320u    // [b][130][130][128] u16 = 34611200

typedef const __attribute__((address_space(1))) unsigned int glob_u32;
typedef __attribute__((address_space(3))) unsigned int lds_u32;

__device__ __forceinline__ u16 f2bf(float f) {
  union { float f; unsigned int u; } v; v.f = f;
  unsigned int r = v.u + 0x7FFFu + ((v.u >> 16) & 1u);
  return (u16)(r >> 16);
}

// ---------------- D1: all input-only jobs, 512 threads/block ----------------
// jobs: [0,1040) k1 pad+partials; [1040,2192) kCW; [2192,2228) R2; [2228,2356) gkT; [2356] fsum
__global__ __launch_bounds__(512) void kD1(
    const float* __restrict__ x, const float* __restrict__ conv1_w,
    const float* __restrict__ dc_w, const float* __restrict__ gk_w,
    const float* __restrict__ fusion_w,
    u16* __restrict__ xpad, float* __restrict__ part, float* __restrict__ cw2,
    float* __restrict__ R2, float* __restrict__ gkT, float* __restrict__ fsum) {
  const int bid = blockIdx.x;
  const int tid = threadIdx.x;
  if (bid < 1040) {
    // k1: b = bid&7 (XCD affinity), rp = bid>>3 in [0,130)
    const int b = bid & 7;
    const int rp = bid >> 3;
    const size_t xpb = ((size_t)b * 130 + rp) * 130 * 128;
    if (rp == 0 || rp == 129) {
      u16x2 z = {0, 0};
      for (int idx = tid; idx < 8320; idx += 512)
        *(u16x2*)(xpad + xpb + (size_t)idx * 2) = z;
      return;
    }
    const int r = rp - 1;
    const int qq = tid >> 6;        // 0..7: 16-col strip
    const int cp = tid & 63;
    const int c = cp * 2;
    u16x2 z = {0, 0};
    if (qq == 0) *(u16x2*)(xpad + xpb + c) = z;
    if (qq == 1) *(u16x2*)(xpad + xpb + (size_t)129 * 128 + c) = z;
    const float* xr = x + ((size_t)b * 16384 + (size_t)r * 128 + qq * 16) * 128 + c;
    u16* xpw = xpad + xpb + (size_t)(qq * 16 + 1) * 128 + c;
    float t0 = 0.f, t1 = 0.f, cf0 = 0.f, cf1 = 0.f, cl0 = 0.f, cl1 = 0.f;
    #pragma unroll
    for (int q = 0; q < 16; ++q) {
      float2 v = *(const float2*)(xr + (size_t)q * 128);
      u16x2 bv = { f2bf(v.x), f2bf(v.y) };
      *(u16x2*)(xpw + (size_t)q * 128) = bv;
      t0 += v.x; t1 += v.y;
      if (q == 0)  { cf0 = v.x; cf1 = v.y; }
      if (q == 15) { cl0 = v.x; cl1 = v.y; }
    }
    __shared__ float red[8][128];
    red[qq][c] = t0; red[qq][c + 1] = t1;
    // part row base for (b,r,j): (((b*128+r)*2+j)*3+s)*128 + c
    float* pb = part + (size_t)((b * 128 + r) * 2) * 3 * 128;
    // strip-edge single-column stats (no reduction needed):
    if (qq == 0) { pb[1 * 128 + c] = cf0; pb[1 * 128 + c + 1] = cf1; }         // j=0 colFirst
    if (qq == 4) { pb[(3 + 1) * 128 + c] = cf0; pb[(3 + 1) * 128 + c + 1] = cf1; } // j=1 colFirst
    if (qq == 3) { pb[2 * 128 + c] = cl0; pb[2 * 128 + c + 1] = cl1; }         // j=0 colLast
    if (qq == 7) { pb[(3 + 2) * 128 + c] = cl0; pb[(3 + 2) * 128 + c + 1] = cl1; } // j=1 colLast
    __syncthreads();
    if (tid < 256) {
      const int j = tid >> 7, cc = tid & 127;
      float T = red[j * 4 + 0][cc] + red[j * 4 + 1][cc] + red[j * 4 + 2][cc] + red[j * 4 + 3][cc];
      pb[j * 3 * 128 + cc] = T;                                                 // s=0 rowTotal
    }
  } else if (bid < 2192) {
    // kCW: cw2[w][t][oc][cin] = conv1_w[(w*128+oc)][cin][t]
    int gid = (bid - 1040) * 512 + tid;     // 0..589823
    int wtl = gid >> 14;
    int w = wtl / 9, t = wtl % 9;
    int oc = (gid >> 7) & 127, cin = gid & 127;
    cw2[gid] = conv1_w[((size_t)(w * 128 + oc) * 128 + cin) * 9 + t];
  } else if (bid < 2228) {
    // R2[pi][c] = sum_o dc_w[w,o]*conv1_w[(w*128+o)*1152 + c*9 + t], pi = w*9+t
    __shared__ float red2[4][128];
    int pi = bid - 2192, w = pi / 9, t = pi % 9;
    int oh = tid >> 7, c = tid & 127;
    float s = 0.f;
    for (int o4 = 0; o4 < 32; ++o4) {
      int o = oh * 32 + o4;
      s += dc_w[w * 128 + o] * conv1_w[((size_t)(w * 128 + o) * 128 + c) * 9 + t];
    }
    red2[oh][c] = s;
    __syncthreads();
    if (oh == 0) R2[pi * 128 + c] = red2[0][c] + red2[1][c] + red2[2][c] + red2[3][c];
  } else if (bid < 2356) {
    int gid = (bid - 2228) * 512 + tid;     // 0..65535
    int w = gid >> 14, j = (gid >> 7) & 127, c = gid & 127;
    gkT[gid] = gk_w[c * 512 + w * 128 + j];
  } else if (tid < 128) {
    float s = 0.f;
    #pragma unroll
    for (int it = 0; it < 32; ++it) {
      float4 v = *(const float4*)(fusion_w + tid * 640 + 512 + it * 4);
      s += v.x + v.y + v.z + v.w;
    }
    fsum[tid] = s;
  }
}

// ---------------- D2: k2 (blocks 0..7) + k34 (blocks 8..583), 256 thr ----------------
__global__ __launch_bounds__(256) void kD2(
    const float* __restrict__ x, const float* __restrict__ part,
    const float* __restrict__ R2, const float* __restrict__ dc_b,
    const float* __restrict__ l1_w, const float* __restrict__ l1_b,
    const float* __restrict__ l2_w, const float* __restrict__ l2_b,
    const float* __restrict__ fusion_w, const float* __restrict__ cw2,
    const float* __restrict__ gkT, float* __restrict__ ww, float* __restrict__ M) {
  const int bid = blockIdx.x;
  const int tid = threadIdx.x;
  if (bid < 8) {
    // ---- k2: SE gate per batch ----
    const int b = bid;
    const int w = tid >> 6, lane = tid & 63;
    __shared__ float red[4];
    float partial = 0.f;
    const int i = w >> 1, j = w & 1;
    const int r0 = i * 64, s0 = j * 64;
    const size_t base = (size_t)b * 16384 * 128;
    #pragma unroll
    for (int k = 0; k < 2; ++k) {
      const int c = lane * 2 + k;
      float T = 0.f, cF = 0.f, cL = 0.f, rF = 0.f, rL = 0.f;
      for (int r64 = 0; r64 < 64; ++r64) {
        const float* pb = part + (size_t)(((b * 128 + (r0 + r64)) * 2 + j) * 3) * 128 + c;
        float tv = pb[0];
        T += tv; cF += pb[128]; cL += pb[256];
        if (r64 == 0) rF = tv;
        if (r64 == 63) rL = tv;
      }
      float c00 = x[base + ((size_t)(r0 + 0)  * 128 + (s0 + 0))  * 128 + c];
      float c0L = x[base + ((size_t)(r0 + 0)  * 128 + (s0 + 63)) * 128 + c];
      float cL0 = x[base + ((size_t)(r0 + 63) * 128 + (s0 + 0))  * 128 + c];
      float cLL = x[base + ((size_t)(r0 + 63) * 128 + (s0 + 63)) * 128 + c];
      float S[9];
      S[0] = T - rL - cL + cLL;
      S[1] = T - rL;
      S[2] = T - rL - cF + cL0;
      S[3] = T - cL;
      S[4] = T;
      S[5] = T - cF;
      S[6] = T - rF - cL + c0L;
      S[7] = T - rF;
      S[8] = T - rF - cF + c00;
      #pragma unroll
      for (int t = 0; t < 9; ++t) partial += S[t] * R2[((w * 9 + t) << 7) + c];
    }
    for (int off = 32; off > 0; off >>= 1) partial += __shfl_xor(partial, off, 64);
    if (lane == 0) red[w] = partial;
    __syncthreads();
    if (tid == 0) {
      float ww0[4];
      #pragma unroll
      for (int w2 = 0; w2 < 4; ++w2) ww0[w2] = red[w2] * (1.f / 4096.f) + dc_b[w2];
      float h1[16];
      for (int i2 = 0; i2 < 16; ++i2) {
        float s = l1_b[i2];
        #pragma unroll
        for (int w2 = 0; w2 < 4; ++w2) s += l1_w[i2 * 4 + w2] * ww0[w2];
        h1[i2] = 0.5f * s * (1.f + erff(s * 0.70710678118654752f));
      }
      for (int w2 = 0; w2 < 4; ++w2) {
        float s = l2_b[w2];
        for (int i2 = 0; i2 < 16; ++i2) s += l2_w[w2 * 16 + i2] * h1[i2];
        ww[b * 4 + w2] = 1.f / (1.f + expf(-s));
      }
    }
  } else {
    // ---- k34: M[wt][o][c] ----
    __shared__ float P_lds[8][128];
    const int bb = bid - 8;
    const int wt = bb >> 4;             // 0..35
    const int og = bb & 15;
    const int w = wt / 9;
    const int o_l = tid >> 5;           // 0..7
    const int o = og * 8 + o_l;
    const int c = (tid & 31) * 4;
    const float* f1 = fusion_w + o * 640 + w * 128;
    const float* f4 = fusion_w + o * 640 + 512;
    const float* cwp = cw2 + (size_t)wt * 16384 + c;
    float a0 = 0, a1 = 0, a2 = 0, a3 = 0, p0 = 0, p1 = 0, p2 = 0, p3 = 0;
    for (int i = 0; i < 128; ++i) {
      float v1 = f1[i], v4 = f4[i];
      float4 cv = *(const float4*)(cwp + (size_t)i * 128);
      a0 += v1 * cv.x; a1 += v1 * cv.y; a2 += v1 * cv.z; a3 += v1 * cv.w;
      p0 += v4 * cv.x; p1 += v4 * cv.y; p2 += v4 * cv.z; p3 += v4 * cv.w;
    }
    *(float4*)(&P_lds[o_l][c]) = make_float4(p0, p1, p2, p3);
    __syncthreads();
    const float* g = gkT + w * 16384 + c;
    for (int jj = 0; jj < 128; ++jj) {
      float pv = P_lds[o_l][jj];
      float4 g4 = *(const float4*)(g + (size_t)jj * 128);
      a0 += pv * g4.x; a1 += pv * g4.y; a2 += pv * g4.z; a3 += pv * g4.w;
    }
    *(float4*)(M + (size_t)wt * 16384 + o * 128 + c) = make_float4(a0, a1, a2, a3);
  }
}

// ---------------- D3: k5 -> keff TRANSPOSED [b][t][cb][o][8c] bf16 ----------------
__global__ __launch_bounds__(256) void k5_keff(
    const float* __restrict__ M, const float* __restrict__ ww,
    const float* __restrict__ fsum, const float* __restrict__ gk_b,
    u16* __restrict__ keff) {
  int gid = blockIdx.x * 256 + threadIdx.x;   // 0..294911
  int b = gid / 36864;
  int rem = gid % 36864;                      // t*4096 + o*32 + cq
  int t = rem / 4096;
  int o = (rem % 4096) / 32;
  int c = (rem % 32) * 4;
  float w0 = ww[b * 4 + 0], w1 = ww[b * 4 + 1], w2 = ww[b * 4 + 2], w3 = ww[b * 4 + 3];
  int mi = rem * 4;                           // == t*16384 + o*128 + c
  float4 m0 = *(const float4*)(M + 0 * 147456 + mi);
  float4 m1 = *(const float4*)(M + 1 * 147456 + mi);
  float4 m2 = *(const float4*)(M + 2 * 147456 + mi);
  float4 m3 = *(const float4*)(M + 3 * 147456 + mi);
  float fs = fsum[o];
  float4 gb = *(const float4*)(gk_b + c);
  float r0 = w0 * m0.x + w1 * m1.x + w2 * m2.x + w3 * m3.x + fs * gb.x;
  float r1 = w0 * m0.y + w1 * m1.y + w2 * m2.y + w3 * m3.y + fs * gb.y;
  float r2 = w0 * m0.z + w1 * m1.z + w2 * m2.z + w3 * m3.z + fs * gb.z;
  float r3 = w0 * m0.w + w1 * m1.w + w2 * m2.w + w3 * m3.w + fs * gb.w;
  u16x4 st = { f2bf(r0), f2bf(r1), f2bf(r2), f2bf(r3) };
  // transposed store: [b][t][cb=c>>3][o][c&7]
  *(u16x4*)(keff + (size_t)b * 147456 + ((t * 16 + (c >> 3)) * 128 + o) * 8 + (c & 7)) = st;
}

// ---------------- D4: k6 — 9-tap MFMA conv, LDS double-buffer via global_load_lds ----------------
// Block = (b, row p): 128 px x 128 o. 512 thr = 8 waves (2m x 4n), wave tile 64m x 32n.
// Weights DMA'd tap-ahead into the other LDS buffer: ONE barrier per tap, zero staging VALU.
// LDS layout per tap: [cb=16][o=128][8c] u16 (32 KB) -> ds_read_b128 at (cb*128+n)*16B, conflict-free.
__global__ __launch_bounds__(512, 4) void k6_conv(
    const u16* __restrict__ xpad, const u16* __restrict__ keff,
    const float* __restrict__ fusion_b, float* __restrict__ out) {
  __shared__ __align__(16) u16 wlds[2][16384];
  const int tid = threadIdx.x;
  const int blk = blockIdx.x;
  const int b = blk & 7;            // XCD affinity
  const int p = blk >> 3;           // 0..127 ascending -> sliding row window per XCD
  const int wid = tid >> 6;
  const int lane = tid & 63;
  const int wm = (wid & 1) * 64;
  const int wn = (wid >> 1) * 32;
  const int quad = lane >> 4;
  const int l16 = lane & 15;

  const u16* kb = keff + (size_t)b * 147456;

  auto stage = [&](int tap, int bufi) {
    const u16* src = kb + tap * 16384;
    char* dstb = (char*)&wlds[bufi][0] + (wid << 10);   // wave-uniform base
    #pragma unroll
    for (int it = 0; it < 4; ++it) {
      __builtin_amdgcn_global_load_lds(
          (glob_u32*)(src + ((it * 512 + tid) << 3)),
          (lds_u32*)(dstb + it * 8192), 16, 0, 0);
    }
  };

  f32x4 acc[4][2];
  #pragma unroll
  for (int i = 0; i < 4; ++i)
    #pragma unroll
    for (int j = 0; j < 2; ++j)
      acc[i][j] = (f32x4){0.f, 0.f, 0.f, 0.f};

  stage(0, 0);
  __builtin_amdgcn_s_waitcnt(0x0F70);   // vmcnt(0)
  __syncthreads();

  const size_t xrow = 130 * 128;
  const u16* xb = xpad + (size_t)b * 130 * xrow;

  for (int tap = 0; tap < 9; ++tap) {
    if (tap < 8) stage(tap + 1, (tap + 1) & 1);   // async DMA, overlaps MFMA below
    const int dh = tap / 3 - 1;
    const int dw = tap % 3 - 1;
    const u16* arow = xb + (size_t)(p + 1 + dh) * xrow + (size_t)(1 + dw) * 128;
    const u16* wbuf = &wlds[tap & 1][0];
    #pragma unroll
    for (int kc = 0; kc < 4; ++kc) {
      const int c0 = kc * 32 + quad * 8;
      const int cb = kc * 4 + quad;
      bf16x8 a[4], bb[2];
      #pragma unroll
      for (int i = 0; i < 4; ++i)
        a[i] = *(const bf16x8*)(arow + (size_t)(wm + i * 16 + l16) * 128 + c0);
      #pragma unroll
      for (int j = 0; j < 2; ++j)
        bb[j] = *(const bf16x8*)(wbuf + ((cb * 128 + (wn + j * 16 + l16)) << 3));
      #pragma unroll
      for (int i = 0; i < 4; ++i)
        #pragma unroll
        for (int j = 0; j < 2; ++j)
          acc[i][j] = __builtin_amdgcn_mfma_f32_16x16x32_bf16(a[i], bb[j], acc[i][j], 0, 0, 0);
    }
    __builtin_amdgcn_s_waitcnt(0x0F70);   // own DMA (tap+1) complete
    __syncthreads();                       // all waves' DMA visible; reads of cur buf done
  }

  float fb[2];
  #pragma unroll
  for (int j = 0; j < 2; ++j) fb[j] = fusion_b[wn + j * 16 + l16];
  float* outb = out + ((size_t)b * 16384 + (size_t)p * 128) * 128;
  #pragma unroll
  for (int i = 0; i < 4; ++i)
    #pragma unroll
    for (int r = 0; r < 4; ++r) {
      const int m = wm + i * 16 + quad * 4 + r;
      #pragma unroll
      for (int j = 0; j < 2; ++j)
        __builtin_nontemporal_store(acc[i][j][r] + fb[j],
                                    &outb[(size_t)m * 128 + (wn + j * 16 + l16)]);
    }
}

extern "C" void kernel_launch(void* const* d_in, const int* in_sizes, int n_in,
                              void* d_out, int out_size, void* d_ws, size_t ws_size,
                              hipStream_t stream) {
  const float* x        = (const float*)d_in[0];
  const float* conv1_w  = (const float*)d_in[1];
  const float* dc_w     = (const float*)d_in[2];
  const float* dc_b     = (const float*)d_in[3];
  const float* l1_w     = (const float*)d_in[4];
  const float* l1_b     = (const float*)d_in[5];
  const float* l2_w     = (const float*)d_in[6];
  const float* l2_b     = (const float*)d_in[7];
  const float* gk_w     = (const float*)d_in[8];
  const float* gk_b     = (const float*)d_in[9];
  const float* fusion_w = (const float*)d_in[10];
  const float* fusion_b = (const float*)d_in[11];
  float* out = (float*)d_out;
  char* ws = (char*)d_ws;

  float* ww   = (float*)(ws + OFF_WW);
  float* R2   = (float*)(ws + OFF_R);
  float* fsum = (float*)(ws + OFF_FSUM);
  float* gkT  = (float*)(ws + OFF_GKT);
  float* part = (float*)(ws + OFF_PART);
  float* M    = (float*)(ws + OFF_M);
  float* cw2  = (float*)(ws + OFF_KEFF);   // cw2 (prep) and keff share the slot
  u16* keff   = (u16*)(ws + OFF_KEFF);
  u16* xpad   = (u16*)(ws + OFF_XPAD);

  kD1<<<2357, 512, 0, stream>>>(x, conv1_w, dc_w, gk_w, fusion_w,
                                xpad, part, cw2, R2, gkT, fsum);
  kD2<<<584, 256, 0, stream>>>(x, part, R2, dc_b, l1_w, l1_b, l2_w, l2_b,
                               fusion_w, cw2, gkT, ww, M);
  k5_keff<<<1152, 256, 0, stream>>>(M, ww, fsum, gk_b, keff);
  k6_conv<<<1024, 512, 0, stream>>>(xpad, keff, fusion_b, out);
}